// Round 3
// baseline (524.410 us; speedup 1.0000x reference)
//
#include <hip/hip_runtime.h>
#include <hip/hip_bf16.h>
#include <math.h>

typedef __bf16 bf16x8 __attribute__((ext_vector_type(8)));
typedef float floatx4 __attribute__((ext_vector_type(4)));

#define ATT_SCALE 0.35355339059327373f  // DH^-0.5, DH=8

__device__ __forceinline__ __bf16 f2b(float x) { return (__bf16)x; }

// ---------------------------------------------------------------------------
// K1: Q = p@wq, Ks = (p@wk)*SCALE, V = p@wv   (2048 rows)
// grid 2048 x 64
// ---------------------------------------------------------------------------
__global__ void k_proj(const float* __restrict__ p,
                       const float* __restrict__ wq, const float* __restrict__ wk,
                       const float* __restrict__ wv,
                       float* __restrict__ Q, float* __restrict__ Ks,
                       float* __restrict__ V) {
  int blk = blockIdx.x, t = threadIdx.x;
  __shared__ float xr[64];
  xr[t] = p[blk * 64 + t];
  __syncthreads();
  float aq = 0.f, ak = 0.f, av = 0.f;
#pragma unroll 8
  for (int c = 0; c < 64; c++) {
    float x = xr[c];
    aq += x * wq[c * 64 + t];
    ak += x * wk[c * 64 + t];
    av += x * wv[c * 64 + t];
  }
  Q[blk * 64 + t] = aq;
  Ks[blk * 64 + t] = ak * ATT_SCALE;
  V[blk * 64 + t] = av;
}

// ---------------------------------------------------------------------------
// K2: edge attention, fused per (b,i) block. Swapped MFMA orientation:
//  D = we^T (A) x e_row^T (B):  D[m=hk_local][n=j] = E[j,hk]
//  lane: col=lane&15 = j-in-tile, row=quad*4+reg = hk_local
//  score head-sum = 3 in-lane adds + 1 shfl_xor(16); Ks/V loads are float4.
// grid 2048 x 256 (4 waves; wave w owns j in [w*64, w*64+64))
// ---------------------------------------------------------------------------
__global__ __launch_bounds__(256) void k_edge(
    const float* __restrict__ e, const float* __restrict__ we,
    const float* __restrict__ krw, const float* __restrict__ mask,
    const float* __restrict__ hin, const float* __restrict__ pin,
    const float* __restrict__ wo, const float* __restrict__ cq_wkv,
    const float* __restrict__ Q, const float* __restrict__ Ks,
    const float* __restrict__ V, float* __restrict__ Kc, float* __restrict__ Vc) {
  int bi = blockIdx.x;          // b*256 + i
  int b = bi >> 8;
  int t = threadIdx.x;
  int w = t >> 6, l = t & 63;
  int l15 = l & 15, q4 = l >> 4;
  int head_lo = q4 >> 1;        // which head within an nt pair

  // A-operand: we^T.  A[m=hk_local(nt tile)][k=c] ; lane m=l15, k=q4*8+jj (+32kc)
  bf16x8 wfrag[4][2];
#pragma unroll
  for (int nt = 0; nt < 4; nt++)
#pragma unroll
    for (int kc = 0; kc < 2; kc++)
#pragma unroll
      for (int jj = 0; jj < 8; jj++)
        wfrag[nt][kc][jj] = f2b(we[(kc * 32 + q4 * 8 + jj) * 64 + nt * 16 + l15]);

  // Q_i for this lane's hk rows: hk = nt*16 + q4*4 + r
  float4 qv[4];
#pragma unroll
  for (int nt = 0; nt < 4; nt++)
    qv[nt] = *reinterpret_cast<const float4*>(Q + bi * 64 + nt * 16 + q4 * 4);

  float mi = mask[bi];

  float aout[4][8];
  float aden[4];
#pragma unroll
  for (int nt = 0; nt < 4; nt++) {
    aden[nt] = 0.f;
#pragma unroll
    for (int dd = 0; dd < 8; dd++) aout[nt][dd] = 0.f;
  }

  for (int mt = 0; mt < 4; mt++) {
    int j0 = w * 64 + mt * 16;
    int j = j0 + l15;
    // B-operand from e: B[k=c][n=j] ; lane n=l15, k=q4*8+jj (+32kc)
    const float* ep = e + ((long)bi * 256 + j) * 64 + q4 * 8;
    float4 ea = *reinterpret_cast<const float4*>(ep);
    float4 eb4 = *reinterpret_cast<const float4*>(ep + 4);
    float4 ec = *reinterpret_cast<const float4*>(ep + 32);
    float4 ed4 = *reinterpret_cast<const float4*>(ep + 36);
    bf16x8 b0, b1;
    b0[0] = f2b(ea.x); b0[1] = f2b(ea.y); b0[2] = f2b(ea.z); b0[3] = f2b(ea.w);
    b0[4] = f2b(eb4.x); b0[5] = f2b(eb4.y); b0[6] = f2b(eb4.z); b0[7] = f2b(eb4.w);
    b1[0] = f2b(ec.x); b1[1] = f2b(ec.y); b1[2] = f2b(ec.z); b1[3] = f2b(ec.w);
    b1[4] = f2b(ed4.x); b1[5] = f2b(ed4.y); b1[6] = f2b(ed4.z); b1[7] = f2b(ed4.w);

    float wkm = krw[(long)bi * 256 + j] * mask[b * 256 + j];
    const float* ksrow = Ks + (b * 256 + j) * 64;
    const float* vrow = V + (b * 256 + j) * 64;

#pragma unroll
    for (int nt = 0; nt < 4; nt++) {
      floatx4 acc = {0.f, 0.f, 0.f, 0.f};
      acc = __builtin_amdgcn_mfma_f32_16x16x32_bf16(wfrag[nt][0], b0, acc, 0, 0, 0);
      acc = __builtin_amdgcn_mfma_f32_16x16x32_bf16(wfrag[nt][1], b1, acc, 0, 0, 0);
      float4 ks4 = *reinterpret_cast<const float4*>(ksrow + nt * 16 + q4 * 4);
      float sp = acc[0] * qv[nt].x * ks4.x + acc[1] * qv[nt].y * ks4.y
               + acc[2] * qv[nt].z * ks4.z + acc[3] * qv[nt].w * ks4.w;
      float s = sp + __shfl_xor(sp, 16);   // combine the two 4-k halves of the head
      float wg = __expf(s) * wkm;
      aden[nt] += wg;
      int head = nt * 2 + head_lo;
      float4 v0 = *reinterpret_cast<const float4*>(vrow + head * 8);
      float4 v1 = *reinterpret_cast<const float4*>(vrow + head * 8 + 4);
      aout[nt][0] += wg * v0.x; aout[nt][1] += wg * v0.y;
      aout[nt][2] += wg * v0.z; aout[nt][3] += wg * v0.w;
      aout[nt][4] += wg * v1.x; aout[nt][5] += wg * v1.y;
      aout[nt][6] += wg * v1.z; aout[nt][7] += wg * v1.w;
    }
  }
  // reduce over the 16 j's held across l15 (mt already accumulated in-register)
#pragma unroll
  for (int nt = 0; nt < 4; nt++) {
    float dn = aden[nt];
    dn += __shfl_xor(dn, 1); dn += __shfl_xor(dn, 2);
    dn += __shfl_xor(dn, 4); dn += __shfl_xor(dn, 8);
    aden[nt] = dn;
#pragma unroll
    for (int dd = 0; dd < 8; dd++) {
      float o = aout[nt][dd];
      o += __shfl_xor(o, 1); o += __shfl_xor(o, 2);
      o += __shfl_xor(o, 4); o += __shfl_xor(o, 8);
      aout[nt][dd] = o;
    }
  }

  __shared__ float red[4][64];
  __shared__ float redden[4][8];
  __shared__ float pav[64];
  __shared__ float hcl[64];
  if (l15 == 0 && (q4 & 1) == 0) {   // one copy per head: q4==0 -> 2nt, q4==2 -> 2nt+1
#pragma unroll
    for (int nt = 0; nt < 4; nt++) {
      int head = nt * 2 + head_lo;
#pragma unroll
      for (int dd = 0; dd < 8; dd++) red[w][head * 8 + dd] = aout[nt][dd];
      redden[w][head] = aden[nt];
    }
  }
  __syncthreads();
  if (t < 64) {
    int head = t >> 3;
    float num = red[0][t] + red[1][t] + red[2][t] + red[3][t];
    float den = redden[0][head] + redden[1][head] + redden[2][head] + redden[3][head];
    num *= mi;
    den = fmaxf(den * mi, 1e-6f);
    pav[t] = num / den;  // p_attn[b,i,head*8+d]
  }
  __syncthreads();
  if (t < 64) {
    float a = 0.f;
#pragma unroll 8
    for (int c = 0; c < 64; c++) a += pav[c] * wo[c * 64 + t];
    hcl[t] = hin[bi * 64 + t] + pin[bi * 64 + t] + tanhf(a);
  }
  __syncthreads();
  if (t < 128) {
    float a = 0.f;
#pragma unroll 8
    for (int c = 0; c < 64; c++) a += hcl[c] * cq_wkv[c * 128 + t];
    if (t < 64) Kc[bi * 64 + t] = a;
    else        Vc[bi * 64 + t - 64] = a;
  }
}

// ---------------------------------------------------------------------------
// K3: whole latent tail in ONE kernel. grid B=8 blocks x 1024 threads.
// Stages (sync between): quer->LDS ; q1=quer@cq_wq ; cross-attn(Kc,Vc,mask) ;
// q=quer+attn@cq_wo+bo ; {qq/kv proj ; self-attn ; q+=attn@wo+bo} x2 ;
// x=q@oq_w ; LN1 ; ffn ; LN2 -> out
// ---------------------------------------------------------------------------
__global__ __launch_bounds__(1024) void k_tail(
    const float* __restrict__ quer, const float* __restrict__ Kc,
    const float* __restrict__ Vc, const float* __restrict__ mask,
    const float* __restrict__ cq_wq, const float* __restrict__ cq_wo,
    const float* __restrict__ cq_bo,
    const float* __restrict__ sa_wq, const float* __restrict__ sa_wkv,
    const float* __restrict__ sa_wo, const float* __restrict__ sa_bo,
    const float* __restrict__ oq_w, const float* __restrict__ g1,
    const float* __restrict__ b1, const float* __restrict__ w1,
    const float* __restrict__ w2, const float* __restrict__ g2,
    const float* __restrict__ b2v, float* __restrict__ out) {
  int b = blockIdx.x;
  int t = threadIdx.x;
  __shared__ float sq[32][64];    // latent state q
  __shared__ float sx[32][64];    // q1 / qq / x / y scratch
  __shared__ float skv[32][128];  // self-attn K|V
  __shared__ float soc[32][64];   // attention output
  __shared__ float shh[32][128];  // ffn hidden

  float* sqf = &sq[0][0];
  float* sxf = &sx[0][0];
  float* skvf = &skv[0][0];
  float* shhf = &shh[0][0];

  // Stage 0: quer -> sq
  sqf[t] = quer[b * 2048 + t];
  sqf[t + 1024] = quer[b * 2048 + t + 1024];
  __syncthreads();

  // Stage 1: q1 = quer @ cq_wq -> sx
#pragma unroll
  for (int half = 0; half < 2; half++) {
    int o = t + half * 1024, r = o >> 6, c = o & 63;
    float a = 0.f;
#pragma unroll 8
    for (int k = 0; k < 64; k++) a += sq[r][k] * cq_wq[k * 64 + c];
    sxf[o] = a;
  }
  __syncthreads();

  // Stage 2: cross-attn over 256 nodes -> soc. t -> (r, h, s)
  {
    int r = t >> 5, h = (t >> 2) & 7, s = t & 3;
    float qv8[8];
#pragma unroll
    for (int dd = 0; dd < 8; dd++) qv8[dd] = sx[r][h * 8 + dd];
    float num[8] = {0.f, 0.f, 0.f, 0.f, 0.f, 0.f, 0.f, 0.f};
    float den = 0.f;
    for (int jj = 0; jj < 64; jj++) {
      int j = s * 64 + jj;
      const float* kp = Kc + ((long)(b * 256 + j)) * 64 + h * 8;
      float4 k0 = *reinterpret_cast<const float4*>(kp);
      float4 k1 = *reinterpret_cast<const float4*>(kp + 4);
      float sc = qv8[0] * k0.x + qv8[1] * k0.y + qv8[2] * k0.z + qv8[3] * k0.w
               + qv8[4] * k1.x + qv8[5] * k1.y + qv8[6] * k1.z + qv8[7] * k1.w;
      sc *= ATT_SCALE;
      sc = (mask[b * 256 + j] > 0.5f) ? sc : -1e30f;
      sc = fminf(fmaxf(sc, -5.f), 5.f);
      float ex = __expf(sc);
      den += ex;
      const float* vp = Vc + ((long)(b * 256 + j)) * 64 + h * 8;
      float4 v0 = *reinterpret_cast<const float4*>(vp);
      float4 v1 = *reinterpret_cast<const float4*>(vp + 4);
      num[0] += ex * v0.x; num[1] += ex * v0.y; num[2] += ex * v0.z; num[3] += ex * v0.w;
      num[4] += ex * v1.x; num[5] += ex * v1.y; num[6] += ex * v1.z; num[7] += ex * v1.w;
    }
    den += __shfl_xor(den, 1); den += __shfl_xor(den, 2);
#pragma unroll
    for (int dd = 0; dd < 8; dd++) {
      float v = num[dd];
      v += __shfl_xor(v, 1); v += __shfl_xor(v, 2);
      num[dd] = v;
    }
    if (s == 0) {
      float inv = 1.f / den;
#pragma unroll
      for (int dd = 0; dd < 8; dd++) soc[r][h * 8 + dd] = num[dd] * inv;
    }
  }
  __syncthreads();

  // Stage 3: q = quer + soc @ cq_wo + cq_bo  (in place into sq)
#pragma unroll
  for (int half = 0; half < 2; half++) {
    int o = t + half * 1024, r = o >> 6, c = o & 63;
    float a = 0.f;
#pragma unroll 8
    for (int k = 0; k < 64; k++) a += soc[r][k] * cq_wo[k * 64 + c];
    sqf[o] = sqf[o] + a + cq_bo[c];
  }
  __syncthreads();

  // Two latent self-attention layers
  for (int layer = 0; layer < 2; layer++) {
    const float* wql = sa_wq + layer * 4096;
    const float* wkvl = sa_wkv + layer * 8192;
    const float* wol = sa_wo + layer * 4096;
    const float* bol = sa_bo + layer * 64;

    // Stage 4: qq -> sx, kv -> skv
#pragma unroll
    for (int half = 0; half < 2; half++) {
      int o = t + half * 1024, r = o >> 6, c = o & 63;
      float a = 0.f;
#pragma unroll 8
      for (int k = 0; k < 64; k++) a += sq[r][k] * wql[k * 64 + c];
      sxf[o] = a;
    }
#pragma unroll
    for (int qu = 0; qu < 4; qu++) {
      int o = t + qu * 1024, r = o >> 7, c = o & 127;
      float a = 0.f;
#pragma unroll 8
      for (int k = 0; k < 64; k++) a += sq[r][k] * wkvl[k * 128 + c];
      skvf[o] = a;
    }
    __syncthreads();

    // Stage 5: self-attn over 32 latents -> soc
    {
      int r = t >> 5, h = (t >> 2) & 7, s = t & 3;
      float qv8[8];
#pragma unroll
      for (int dd = 0; dd < 8; dd++) qv8[dd] = sx[r][h * 8 + dd];
      float num[8] = {0.f, 0.f, 0.f, 0.f, 0.f, 0.f, 0.f, 0.f};
      float den = 0.f;
#pragma unroll
      for (int jj = 0; jj < 8; jj++) {
        int j = s * 8 + jj;
        float sc = 0.f;
#pragma unroll
        for (int dd = 0; dd < 8; dd++) sc += qv8[dd] * skv[j][h * 8 + dd];
        sc *= ATT_SCALE;
        sc = fminf(fmaxf(sc, -5.f), 5.f);
        float ex = __expf(sc);
        den += ex;
#pragma unroll
        for (int dd = 0; dd < 8; dd++) num[dd] += ex * skv[j][64 + h * 8 + dd];
      }
      den += __shfl_xor(den, 1); den += __shfl_xor(den, 2);
#pragma unroll
      for (int dd = 0; dd < 8; dd++) {
        float v = num[dd];
        v += __shfl_xor(v, 1); v += __shfl_xor(v, 2);
        num[dd] = v;
      }
      if (s == 0) {
        float inv = 1.f / den;
#pragma unroll
        for (int dd = 0; dd < 8; dd++) soc[r][h * 8 + dd] = num[dd] * inv;
      }
    }
    __syncthreads();

    // Stage 6: q = q + soc @ wol + bol
#pragma unroll
    for (int half = 0; half < 2; half++) {
      int o = t + half * 1024, r = o >> 6, c = o & 63;
      float a = 0.f;
#pragma unroll 8
      for (int k = 0; k < 64; k++) a += soc[r][k] * wol[k * 64 + c];
      sqf[o] = sqf[o] + a + bol[c];
    }
    __syncthreads();
  }

  // Stage 7a: x = q @ oq_w -> sx
#pragma unroll
  for (int half = 0; half < 2; half++) {
    int o = t + half * 1024, r = o >> 6, c = o & 63;
    float a = 0.f;
#pragma unroll 8
    for (int k = 0; k < 64; k++) a += sq[r][k] * oq_w[k * 64 + c];
    sxf[o] = a;
  }
  __syncthreads();

  // Stage 7b: LN1 in place on sx (wave per row, 2 rows per wave)
  {
    int wv = t >> 6, lc = t & 63;
#pragma unroll
    for (int pass = 0; pass < 2; pass++) {
      int r = wv + pass * 16;
      float x = sx[r][lc];
      float m = x;
      for (int off = 1; off < 64; off <<= 1) m += __shfl_xor(m, off);
      m *= (1.f / 64.f);
      float dv = x - m, vv = dv * dv;
      for (int off = 1; off < 64; off <<= 1) vv += __shfl_xor(vv, off);
      vv *= (1.f / 64.f);
      sx[r][lc] = dv * rsqrtf(vv + 1e-5f) * g1[lc] + b1[lc];
    }
  }
  __syncthreads();

  // Stage 8: hh = relu(y @ w1) -> shh
#pragma unroll
  for (int qu = 0; qu < 4; qu++) {
    int o = t + qu * 1024, r = o >> 7, c = o & 127;
    float a = 0.f;
#pragma unroll 8
    for (int k = 0; k < 64; k++) a += sx[r][k] * w1[k * 128 + c];
    shhf[o] = fmaxf(a, 0.f);
  }
  __syncthreads();

  // Stage 9: z = y + hh @ w2 ; LN2 ; write out  (wave per row)
  {
    int wv = t >> 6, lc = t & 63;
#pragma unroll
    for (int pass = 0; pass < 2; pass++) {
      int r = wv + pass * 16;
      float ff = 0.f;
#pragma unroll 8
      for (int k = 0; k < 128; k++) ff += shh[r][k] * w2[k * 64 + lc];
      float z = sx[r][lc] + ff;
      float m2 = z;
      for (int off = 1; off < 64; off <<= 1) m2 += __shfl_xor(m2, off);
      m2 *= (1.f / 64.f);
      float dz = z - m2, v2 = dz * dz;
      for (int off = 1; off < 64; off <<= 1) v2 += __shfl_xor(v2, off);
      v2 *= (1.f / 64.f);
      out[b * 2048 + r * 64 + lc] = dz * rsqrtf(v2 + 1e-5f) * g2[lc] + b2v[lc];
    }
  }
}

// ---------------------------------------------------------------------------
extern "C" void kernel_launch(void* const* d_in, const int* in_sizes, int n_in,
                              void* d_out, int out_size, void* d_ws, size_t ws_size,
                              hipStream_t stream) {
  const float* h_in   = (const float*)d_in[0];
  const float* p_in   = (const float*)d_in[1];
  const float* e_in   = (const float*)d_in[2];
  const float* krw    = (const float*)d_in[3];
  const float* quer   = (const float*)d_in[4];
  const float* mask   = (const float*)d_in[5];
  const float* wq_p   = (const float*)d_in[6];
  const float* wk_p   = (const float*)d_in[7];
  const float* we_p   = (const float*)d_in[8];
  const float* wv_p   = (const float*)d_in[9];
  const float* wo_p   = (const float*)d_in[10];
  const float* cq_wq  = (const float*)d_in[11];
  const float* cq_wkv = (const float*)d_in[12];
  const float* cq_wo  = (const float*)d_in[13];
  const float* cq_bo  = (const float*)d_in[14];
  const float* sa_wq  = (const float*)d_in[15];
  const float* sa_wkv = (const float*)d_in[16];
  const float* sa_wo  = (const float*)d_in[17];
  const float* sa_bo  = (const float*)d_in[18];
  const float* oq_w   = (const float*)d_in[19];
  const float* ln1_g  = (const float*)d_in[20];
  const float* ln1_b  = (const float*)d_in[21];
  const float* ffn_w1 = (const float*)d_in[22];
  const float* ffn_w2 = (const float*)d_in[23];
  const float* ln2_g  = (const float*)d_in[24];
  const float* ln2_b  = (const float*)d_in[25];

  float* ws = (float*)d_ws;
  float* Q  = ws;              // 131072
  float* Ks = Q + 131072;      // 131072
  float* V  = Ks + 131072;     // 131072
  float* Kc = V + 131072;      // 131072
  float* Vc = Kc + 131072;     // 131072  total 2.6 MB

  k_proj<<<2048, 64, 0, stream>>>(p_in, wq_p, wk_p, wv_p, Q, Ks, V);
  k_edge<<<2048, 256, 0, stream>>>(e_in, we_p, krw, mask, h_in, p_in, wo_p, cq_wkv,
                                   Q, Ks, V, Kc, Vc);
  k_tail<<<8, 1024, 0, stream>>>(quer, Kc, Vc, mask, cq_wq, cq_wo, cq_bo,
                                 sa_wq, sa_wkv, sa_wo, sa_bo, oq_w,
                                 ln1_g, ln1_b, ffn_w1, ffn_w2, ln2_g, ln2_b,
                                 (float*)d_out);
}

// Round 4
// 373.854 us; speedup vs baseline: 1.4027x; 1.4027x over previous
//
#include <hip/hip_runtime.h>
#include <hip/hip_bf16.h>
#include <math.h>

typedef __bf16 bf16x8 __attribute__((ext_vector_type(8)));
typedef float floatx4 __attribute__((ext_vector_type(4)));

#define ATT_SCALE 0.35355339059327373f  // DH^-0.5, DH=8

__device__ __forceinline__ __bf16 f2b(float x) { return (__bf16)x; }

// ---------------------------------------------------------------------------
// K1: Q = p@wq, Ks = (p@wk)*SCALE, V = p@wv   (2048 rows)
// grid 2048 x 64
// ---------------------------------------------------------------------------
__global__ void k_proj(const float* __restrict__ p,
                       const float* __restrict__ wq, const float* __restrict__ wk,
                       const float* __restrict__ wv,
                       float* __restrict__ Q, float* __restrict__ Ks,
                       float* __restrict__ V) {
  int blk = blockIdx.x, t = threadIdx.x;
  __shared__ float xr[64];
  xr[t] = p[blk * 64 + t];
  __syncthreads();
  float aq = 0.f, ak = 0.f, av = 0.f;
#pragma unroll 8
  for (int c = 0; c < 64; c++) {
    float x = xr[c];
    aq += x * wq[c * 64 + t];
    ak += x * wk[c * 64 + t];
    av += x * wv[c * 64 + t];
  }
  Q[blk * 64 + t] = aq;
  Ks[blk * 64 + t] = ak * ATT_SCALE;
  V[blk * 64 + t] = av;
}

// ---------------------------------------------------------------------------
// K2: edge attention — EXACT round-2 version (ran at HBM floor ~77us).
// grid 2048 x 256 (4 waves; wave w owns j in [w*64, w*64+64))
// ---------------------------------------------------------------------------
__global__ __launch_bounds__(256) void k_edge(
    const float* __restrict__ e, const float* __restrict__ we,
    const float* __restrict__ krw, const float* __restrict__ mask,
    const float* __restrict__ hin, const float* __restrict__ pin,
    const float* __restrict__ wo, const float* __restrict__ cq_wkv,
    const float* __restrict__ Q, const float* __restrict__ Ks,
    const float* __restrict__ V, float* __restrict__ Kc, float* __restrict__ Vc) {
  int bi = blockIdx.x;          // b*256 + i
  int b = bi >> 8;
  int t = threadIdx.x;
  int w = t >> 6, l = t & 63;
  int l15 = l & 15, quad = l >> 4, half8 = (l >> 3) & 1, d = l & 7;

  // B-fragments of we: B[k=quad*8+jj][n=l15], per n-tile (nt) and K-chunk (kc)
  bf16x8 wfrag[4][2];
#pragma unroll
  for (int nt = 0; nt < 4; nt++)
#pragma unroll
    for (int kc = 0; kc < 2; kc++)
#pragma unroll
      for (int jj = 0; jj < 8; jj++)
        wfrag[nt][kc][jj] = f2b(we[(kc * 32 + quad * 8 + jj) * 64 + nt * 16 + l15]);

  float qv[4];
#pragma unroll
  for (int nt = 0; nt < 4; nt++) qv[nt] = Q[bi * 64 + nt * 16 + l15];
  float mi = mask[bi];

  float aout[4] = {0.f, 0.f, 0.f, 0.f};
  float aden[4] = {0.f, 0.f, 0.f, 0.f};

  for (int mt = 0; mt < 4; mt++) {
    int j0 = w * 64 + mt * 16;
    // A-fragments from global e (fp32), converted: A[m=l15][k=quad*8+jj]
    const float* ep = e + ((long)bi * 256 + j0 + l15) * 64 + quad * 8;
    float4 ea = *reinterpret_cast<const float4*>(ep);
    float4 eb4 = *reinterpret_cast<const float4*>(ep + 4);
    float4 ec = *reinterpret_cast<const float4*>(ep + 32);
    float4 ed4 = *reinterpret_cast<const float4*>(ep + 36);
    bf16x8 a0, a1;
    a0[0] = f2b(ea.x); a0[1] = f2b(ea.y); a0[2] = f2b(ea.z); a0[3] = f2b(ea.w);
    a0[4] = f2b(eb4.x); a0[5] = f2b(eb4.y); a0[6] = f2b(eb4.z); a0[7] = f2b(eb4.w);
    a1[0] = f2b(ec.x); a1[1] = f2b(ec.y); a1[2] = f2b(ec.z); a1[3] = f2b(ec.w);
    a1[4] = f2b(ed4.x); a1[5] = f2b(ed4.y); a1[6] = f2b(ed4.z); a1[7] = f2b(ed4.w);

    int jr0 = j0 + quad * 4;  // D rows this lane owns: jr0..jr0+3
    float krw_r[4], mj_r[4];
#pragma unroll
    for (int r = 0; r < 4; r++) {
      krw_r[r] = krw[(long)bi * 256 + jr0 + r];
      mj_r[r] = mask[b * 256 + jr0 + r];
    }
#pragma unroll
    for (int nt = 0; nt < 4; nt++) {
      floatx4 acc = {0.f, 0.f, 0.f, 0.f};
      acc = __builtin_amdgcn_mfma_f32_16x16x32_bf16(a0, wfrag[nt][0], acc, 0, 0, 0);
      acc = __builtin_amdgcn_mfma_f32_16x16x32_bf16(a1, wfrag[nt][1], acc, 0, 0, 0);
      int hk = nt * 16 + l15;      // D col = lane&15
      int hbase = hk & 56;         // head*8
#pragma unroll
      for (int r = 0; r < 4; r++) {
        int jr = jr0 + r;          // D row = quad*4 + r
        float s = acc[r] * qv[nt] * Ks[(b * 256 + jr) * 64 + hk];
        s += __shfl_xor(s, 1);
        s += __shfl_xor(s, 2);
        s += __shfl_xor(s, 4);
        float wg = __expf(s) * krw_r[r] * mj_r[r];
        aden[nt] += wg;
        aout[nt] += wg * V[(b * 256 + jr) * 64 + hbase + d];
      }
    }
  }
#pragma unroll
  for (int nt = 0; nt < 4; nt++) {
    float o = aout[nt], dn = aden[nt];
    o += __shfl_xor(o, 16); o += __shfl_xor(o, 32);
    dn += __shfl_xor(dn, 16); dn += __shfl_xor(dn, 32);
    aout[nt] = o; aden[nt] = dn;
  }

  __shared__ float red[4][64];
  __shared__ float redden[4][8];
  __shared__ float pav[64];
  __shared__ float hcl[64];
  if (l < 16) {
#pragma unroll
    for (int nt = 0; nt < 4; nt++) {
      int head = nt * 2 + half8;
      red[w][head * 8 + d] = aout[nt];
      if (d == 0) redden[w][head] = aden[nt];
    }
  }
  __syncthreads();
  if (t < 64) {
    int head = t >> 3;
    float num = red[0][t] + red[1][t] + red[2][t] + red[3][t];
    float den = redden[0][head] + redden[1][head] + redden[2][head] + redden[3][head];
    num *= mi;
    den = fmaxf(den * mi, 1e-6f);
    pav[t] = num / den;
  }
  __syncthreads();
  if (t < 64) {
    float a = 0.f;
#pragma unroll 8
    for (int c = 0; c < 64; c++) a += pav[c] * wo[c * 64 + t];
    hcl[t] = hin[bi * 64 + t] + pin[bi * 64 + t] + tanhf(a);
  }
  __syncthreads();
  if (t < 128) {
    float a = 0.f;
#pragma unroll 8
    for (int c = 0; c < 64; c++) a += hcl[c] * cq_wkv[c * 128 + t];
    if (t < 64) Kc[bi * 64 + t] = a;
    else        Vc[bi * 64 + t - 64] = a;
  }
}

// ---------------------------------------------------------------------------
// K3: fused latent tail, one block per batch, 1024 threads.
// Cross-attn K/V staged in LDS (64-row quarters, stride 68 = conflict-padded,
// j interleaved as 4*jj+s). pool[] aliased: K/V stage -> self-attn KV -> FFN h.
// Static LDS total = 62 KB.
// ---------------------------------------------------------------------------
__global__ __launch_bounds__(1024) void k_tail(
    const float* __restrict__ quer, const float* __restrict__ Kc,
    const float* __restrict__ Vc, const float* __restrict__ mask,
    const float* __restrict__ cq_wq, const float* __restrict__ cq_wo,
    const float* __restrict__ cq_bo,
    const float* __restrict__ sa_wq, const float* __restrict__ sa_wkv,
    const float* __restrict__ sa_wo, const float* __restrict__ sa_bo,
    const float* __restrict__ oq_w, const float* __restrict__ g1,
    const float* __restrict__ b1, const float* __restrict__ w1,
    const float* __restrict__ w2, const float* __restrict__ g2,
    const float* __restrict__ b2v, float* __restrict__ out) {
  int b = blockIdx.x;
  int t = threadIdx.x;

  __shared__ float pool[8704];   // phase-aliased scratch (34.8 KB)
  __shared__ float sq[32 * 68];  // latent state
  __shared__ float sx[32 * 68];  // q1 / qq / x / y
  __shared__ float soc[32 * 68]; // attention out
  __shared__ float smask[256];

  // Stage 0: quer -> sq, mask -> smask
  {
    int r0 = t >> 5, c2 = (t & 31) * 2;
    sq[r0 * 68 + c2]     = quer[b * 2048 + r0 * 64 + c2];
    sq[r0 * 68 + c2 + 1] = quer[b * 2048 + r0 * 64 + c2 + 1];
    if (t < 256) smask[t] = mask[b * 256 + t];
  }
  __syncthreads();

  // Stage 1: q1 = quer @ cq_wq -> sx
#pragma unroll
  for (int half = 0; half < 2; half++) {
    int o = t + half * 1024, rr = o >> 6, c = o & 63;
    float a = 0.f;
#pragma unroll 8
    for (int k = 0; k < 64; k++) a += sq[rr * 68 + k] * cq_wq[k * 64 + c];
    sx[rr * 68 + c] = a;
  }
  __syncthreads();

  // Stage 2: cross-attn, K/V quarters staged in LDS
  int r = t >> 5, h = (t >> 2) & 7, s = t & 3;
  {
    float qv8[8];
#pragma unroll
    for (int dd = 0; dd < 8; dd++) qv8[dd] = sx[r * 68 + h * 8 + dd];
    float num[8] = {0.f, 0.f, 0.f, 0.f, 0.f, 0.f, 0.f, 0.f};
    float den = 0.f;
    for (int qtr = 0; qtr < 4; qtr++) {
      {
        int jl = t >> 4, c4 = (t & 15) * 4;
        long row = (long)(b * 256 + qtr * 64 + jl) * 64 + c4;
        float4 kk = *reinterpret_cast<const float4*>(Kc + row);
        float4 vv = *reinterpret_cast<const float4*>(Vc + row);
        *reinterpret_cast<float4*>(&pool[jl * 68 + c4]) = kk;
        *reinterpret_cast<float4*>(&pool[64 * 68 + jl * 68 + c4]) = vv;
      }
      __syncthreads();
#pragma unroll
      for (int jj = 0; jj < 16; jj++) {
        int jl = jj * 4 + s;
        const float* kp = &pool[jl * 68 + h * 8];
        float4 k0 = *reinterpret_cast<const float4*>(kp);
        float4 k1 = *reinterpret_cast<const float4*>(kp + 4);
        float sc = qv8[0] * k0.x + qv8[1] * k0.y + qv8[2] * k0.z + qv8[3] * k0.w
                 + qv8[4] * k1.x + qv8[5] * k1.y + qv8[6] * k1.z + qv8[7] * k1.w;
        sc *= ATT_SCALE;
        sc = (smask[qtr * 64 + jl] > 0.5f) ? sc : -1e30f;
        sc = fminf(fmaxf(sc, -5.f), 5.f);
        float ex = __expf(sc);
        den += ex;
        const float* vp = &pool[64 * 68 + jl * 68 + h * 8];
        float4 v0 = *reinterpret_cast<const float4*>(vp);
        float4 v1 = *reinterpret_cast<const float4*>(vp + 4);
        num[0] += ex * v0.x; num[1] += ex * v0.y; num[2] += ex * v0.z; num[3] += ex * v0.w;
        num[4] += ex * v1.x; num[5] += ex * v1.y; num[6] += ex * v1.z; num[7] += ex * v1.w;
      }
      __syncthreads();
    }
    den += __shfl_xor(den, 1); den += __shfl_xor(den, 2);
#pragma unroll
    for (int dd = 0; dd < 8; dd++) {
      float v = num[dd];
      v += __shfl_xor(v, 1); v += __shfl_xor(v, 2);
      num[dd] = v;
    }
    if (s == 0) {
      float inv = 1.f / den;
#pragma unroll
      for (int dd = 0; dd < 8; dd++) soc[r * 68 + h * 8 + dd] = num[dd] * inv;
    }
  }
  __syncthreads();

  // Stage 3: q = quer + soc @ cq_wo + cq_bo
#pragma unroll
  for (int half = 0; half < 2; half++) {
    int o = t + half * 1024, rr = o >> 6, c = o & 63;
    float a = 0.f;
#pragma unroll 8
    for (int k = 0; k < 64; k++) a += soc[rr * 68 + k] * cq_wo[k * 64 + c];
    sq[rr * 68 + c] += a + cq_bo[c];
  }
  __syncthreads();

  // Two latent self-attention layers; self-attn KV in pool (stride 65)
  for (int layer = 0; layer < 2; layer++) {
    const float* wql = sa_wq + layer * 4096;
    const float* wkvl = sa_wkv + layer * 8192;
    const float* wol = sa_wo + layer * 4096;
    const float* bol = sa_bo + layer * 64;

#pragma unroll
    for (int half = 0; half < 2; half++) {
      int o = t + half * 1024, rr = o >> 6, c = o & 63;
      float a = 0.f;
#pragma unroll 8
      for (int k = 0; k < 64; k++) a += sq[rr * 68 + k] * wql[k * 64 + c];
      sx[rr * 68 + c] = a;
    }
#pragma unroll
    for (int qu = 0; qu < 4; qu++) {
      int o = t + qu * 1024, rr = o >> 7, c = o & 127;
      float a = 0.f;
#pragma unroll 8
      for (int k = 0; k < 64; k++) a += sq[rr * 68 + k] * wkvl[k * 128 + c];
      if (c < 64) pool[rr * 65 + c] = a;
      else        pool[2080 + rr * 65 + (c - 64)] = a;
    }
    __syncthreads();

    {
      float qv[8];
#pragma unroll
      for (int dd = 0; dd < 8; dd++) qv[dd] = sx[r * 68 + h * 8 + dd];
      float nm[8] = {0.f, 0.f, 0.f, 0.f, 0.f, 0.f, 0.f, 0.f};
      float dn = 0.f;
#pragma unroll
      for (int jj = 0; jj < 8; jj++) {
        int j = jj * 4 + s;
        const float* kp = &pool[j * 65 + h * 8];
        float sc = 0.f;
#pragma unroll
        for (int dd = 0; dd < 8; dd++) sc += qv[dd] * kp[dd];
        sc *= ATT_SCALE;
        sc = fminf(fmaxf(sc, -5.f), 5.f);
        float ex = __expf(sc);
        dn += ex;
        const float* vp = &pool[2080 + j * 65 + h * 8];
#pragma unroll
        for (int dd = 0; dd < 8; dd++) nm[dd] += ex * vp[dd];
      }
      dn += __shfl_xor(dn, 1); dn += __shfl_xor(dn, 2);
#pragma unroll
      for (int dd = 0; dd < 8; dd++) {
        float v = nm[dd];
        v += __shfl_xor(v, 1); v += __shfl_xor(v, 2);
        nm[dd] = v;
      }
      if (s == 0) {
        float inv = 1.f / dn;
#pragma unroll
        for (int dd = 0; dd < 8; dd++) soc[r * 68 + h * 8 + dd] = nm[dd] * inv;
      }
    }
    __syncthreads();

#pragma unroll
    for (int half = 0; half < 2; half++) {
      int o = t + half * 1024, rr = o >> 6, c = o & 63;
      float a = 0.f;
#pragma unroll 8
      for (int k = 0; k < 64; k++) a += soc[rr * 68 + k] * wol[k * 64 + c];
      sq[rr * 68 + c] += a + bol[c];
    }
    __syncthreads();
  }

  // Stage 7: x = q @ oq_w -> sx ; LN1 in place
#pragma unroll
  for (int half = 0; half < 2; half++) {
    int o = t + half * 1024, rr = o >> 6, c = o & 63;
    float a = 0.f;
#pragma unroll 8
    for (int k = 0; k < 64; k++) a += sq[rr * 68 + k] * oq_w[k * 64 + c];
    sx[rr * 68 + c] = a;
  }
  __syncthreads();
  {
    int wv = t >> 6, lc = t & 63;
#pragma unroll
    for (int pass = 0; pass < 2; pass++) {
      int rr = wv + pass * 16;
      float x = sx[rr * 68 + lc];
      float m = x;
      for (int off = 1; off < 64; off <<= 1) m += __shfl_xor(m, off);
      m *= (1.f / 64.f);
      float dv = x - m, vv = dv * dv;
      for (int off = 1; off < 64; off <<= 1) vv += __shfl_xor(vv, off);
      vv *= (1.f / 64.f);
      sx[rr * 68 + lc] = dv * rsqrtf(vv + 1e-5f) * g1[lc] + b1[lc];
    }
  }
  __syncthreads();

  // Stage 8: hh = relu(y @ w1) -> pool (stride 128)
#pragma unroll
  for (int qu = 0; qu < 4; qu++) {
    int o = t + qu * 1024, rr = o >> 7, c = o & 127;
    float a = 0.f;
#pragma unroll 8
    for (int k = 0; k < 64; k++) a += sx[rr * 68 + k] * w1[k * 128 + c];
    pool[rr * 128 + c] = fmaxf(a, 0.f);
  }
  __syncthreads();

  // Stage 9: z = y + hh @ w2 ; LN2 ; out
  {
    int wv = t >> 6, lc = t & 63;
#pragma unroll
    for (int pass = 0; pass < 2; pass++) {
      int rr = wv + pass * 16;
      float ff = 0.f;
#pragma unroll 8
      for (int k = 0; k < 128; k++) ff += pool[rr * 128 + k] * w2[k * 64 + lc];
      float z = sx[rr * 68 + lc] + ff;
      float m2 = z;
      for (int off = 1; off < 64; off <<= 1) m2 += __shfl_xor(m2, off);
      m2 *= (1.f / 64.f);
      float dz = z - m2, v2 = dz * dz;
      for (int off = 1; off < 64; off <<= 1) v2 += __shfl_xor(v2, off);
      v2 *= (1.f / 64.f);
      out[b * 2048 + rr * 64 + lc] = dz * rsqrtf(v2 + 1e-5f) * g2[lc] + b2v[lc];
    }
  }
}

// ---------------------------------------------------------------------------
extern "C" void kernel_launch(void* const* d_in, const int* in_sizes, int n_in,
                              void* d_out, int out_size, void* d_ws, size_t ws_size,
                              hipStream_t stream) {
  const float* h_in   = (const float*)d_in[0];
  const float* p_in   = (const float*)d_in[1];
  const float* e_in   = (const float*)d_in[2];
  const float* krw    = (const float*)d_in[3];
  const float* quer   = (const float*)d_in[4];
  const float* mask   = (const float*)d_in[5];
  const float* wq_p   = (const float*)d_in[6];
  const float* wk_p   = (const float*)d_in[7];
  const float* we_p   = (const float*)d_in[8];
  const float* wv_p   = (const float*)d_in[9];
  const float* wo_p   = (const float*)d_in[10];
  const float* cq_wq  = (const float*)d_in[11];
  const float* cq_wkv = (const float*)d_in[12];
  const float* cq_wo  = (const float*)d_in[13];
  const float* cq_bo  = (const float*)d_in[14];
  const float* sa_wq  = (const float*)d_in[15];
  const float* sa_wkv = (const float*)d_in[16];
  const float* sa_wo  = (const float*)d_in[17];
  const float* sa_bo  = (const float*)d_in[18];
  const float* oq_w   = (const float*)d_in[19];
  const float* ln1_g  = (const float*)d_in[20];
  const float* ln1_b  = (const float*)d_in[21];
  const float* ffn_w1 = (const float*)d_in[22];
  const float* ffn_w2 = (const float*)d_in[23];
  const float* ln2_g  = (const float*)d_in[24];
  const float* ln2_b  = (const float*)d_in[25];

  float* ws = (float*)d_ws;
  float* Q  = ws;              // 131072
  float* Ks = Q + 131072;      // 131072
  float* V  = Ks + 131072;     // 131072
  float* Kc = V + 131072;      // 131072
  float* Vc = Kc + 131072;     // 131072  total 2.6 MB

  k_proj<<<2048, 64, 0, stream>>>(p_in, wq_p, wk_p, wv_p, Q, Ks, V);
  k_edge<<<2048, 256, 0, stream>>>(e_in, we_p, krw, mask, h_in, p_in, wo_p, cq_wkv,
                                   Q, Ks, V, Kc, Vc);
  k_tail<<<8, 1024, 0, stream>>>(quer, Kc, Vc, mask, cq_wq, cq_wo, cq_bo,
                                 sa_wq, sa_wkv, sa_wo, sa_bo, oq_w,
                                 ln1_g, ln1_b, ffn_w1, ffn_w2, ln2_g, ln2_b,
                                 (float*)d_out);
}

// Round 5
// 333.196 us; speedup vs baseline: 1.5739x; 1.1220x over previous
//
#include <hip/hip_runtime.h>
#include <hip/hip_bf16.h>
#include <math.h>

typedef __bf16 bf16x8 __attribute__((ext_vector_type(8)));
typedef float floatx4 __attribute__((ext_vector_type(4)));

#define ATT_SCALE 0.35355339059327373f  // DH^-0.5, DH=8

__device__ __forceinline__ __bf16 f2b(float x) { return (__bf16)x; }

// ---------------------------------------------------------------------------
// K1: Q = p@wq, Ks = (p@wk)*SCALE, V = p@wv. 256 blocks x 256 thr, 8 rows/blk.
// ---------------------------------------------------------------------------
__global__ __launch_bounds__(256) void k_proj(const float* __restrict__ p,
                       const float* __restrict__ wq, const float* __restrict__ wk,
                       const float* __restrict__ wv,
                       float* __restrict__ Q, float* __restrict__ Ks,
                       float* __restrict__ V) {
  int blk = blockIdx.x, t = threadIdx.x;
  __shared__ float xr[8][64];
  {
    int rr = t >> 5, cc = (t & 31) * 2;
    float2 pz = *reinterpret_cast<const float2*>(p + blk * 512 + rr * 64 + cc);
    xr[rr][cc] = pz.x; xr[rr][cc + 1] = pz.y;
  }
  __syncthreads();
  if (t < 192) {
    int mat = t >> 6, c = t & 63;
    const float* w = (mat == 0) ? wq : ((mat == 1) ? wk : wv);
    float acc[8] = {0.f, 0.f, 0.f, 0.f, 0.f, 0.f, 0.f, 0.f};
#pragma unroll 8
    for (int k = 0; k < 64; k++) {
      float wv_ = w[k * 64 + c];
#pragma unroll
      for (int r = 0; r < 8; r++) acc[r] += xr[r][k] * wv_;
    }
    float* dst = (mat == 0) ? Q : ((mat == 1) ? Ks : V);
    float sc = (mat == 1) ? ATT_SCALE : 1.f;
#pragma unroll
    for (int r = 0; r < 8; r++) dst[(blk * 8 + r) * 64 + c] = acc[r] * sc;
  }
}

// ---------------------------------------------------------------------------
// K2: edge attention — byte-identical to the round-2 version (≈HBM floor).
// ---------------------------------------------------------------------------
__global__ __launch_bounds__(256) void k_edge(
    const float* __restrict__ e, const float* __restrict__ we,
    const float* __restrict__ krw, const float* __restrict__ mask,
    const float* __restrict__ hin, const float* __restrict__ pin,
    const float* __restrict__ wo, const float* __restrict__ cq_wkv,
    const float* __restrict__ Q, const float* __restrict__ Ks,
    const float* __restrict__ V, float* __restrict__ Kc, float* __restrict__ Vc) {
  int bi = blockIdx.x;          // b*256 + i
  int b = bi >> 8;
  int t = threadIdx.x;
  int w = t >> 6, l = t & 63;
  int l15 = l & 15, quad = l >> 4, half8 = (l >> 3) & 1, d = l & 7;

  bf16x8 wfrag[4][2];
  for (int nt = 0; nt < 4; nt++)
    for (int kc = 0; kc < 2; kc++)
      for (int jj = 0; jj < 8; jj++)
        wfrag[nt][kc][jj] = f2b(we[(kc * 32 + quad * 8 + jj) * 64 + nt * 16 + l15]);

  float qv[4];
  for (int nt = 0; nt < 4; nt++) qv[nt] = Q[bi * 64 + nt * 16 + l15];
  float mi = mask[bi];

  float aout[4] = {0.f, 0.f, 0.f, 0.f};
  float aden[4] = {0.f, 0.f, 0.f, 0.f};

  for (int mt = 0; mt < 4; mt++) {
    int j0 = w * 64 + mt * 16;
    const float* ep = e + ((long)bi * 256 + j0 + l15) * 64 + quad * 8;
    float4 ea = *reinterpret_cast<const float4*>(ep);
    float4 eb4 = *reinterpret_cast<const float4*>(ep + 4);
    float4 ec = *reinterpret_cast<const float4*>(ep + 32);
    float4 ed4 = *reinterpret_cast<const float4*>(ep + 36);
    bf16x8 a0, a1;
    a0[0] = f2b(ea.x); a0[1] = f2b(ea.y); a0[2] = f2b(ea.z); a0[3] = f2b(ea.w);
    a0[4] = f2b(eb4.x); a0[5] = f2b(eb4.y); a0[6] = f2b(eb4.z); a0[7] = f2b(eb4.w);
    a1[0] = f2b(ec.x); a1[1] = f2b(ec.y); a1[2] = f2b(ec.z); a1[3] = f2b(ec.w);
    a1[4] = f2b(ed4.x); a1[5] = f2b(ed4.y); a1[6] = f2b(ed4.z); a1[7] = f2b(ed4.w);

    int jr0 = j0 + quad * 4;
    float krw_r[4], mj_r[4];
    for (int r = 0; r < 4; r++) {
      krw_r[r] = krw[(long)bi * 256 + jr0 + r];
      mj_r[r] = mask[b * 256 + jr0 + r];
    }
    for (int nt = 0; nt < 4; nt++) {
      floatx4 acc = {0.f, 0.f, 0.f, 0.f};
      acc = __builtin_amdgcn_mfma_f32_16x16x32_bf16(a0, wfrag[nt][0], acc, 0, 0, 0);
      acc = __builtin_amdgcn_mfma_f32_16x16x32_bf16(a1, wfrag[nt][1], acc, 0, 0, 0);
      int hk = nt * 16 + l15;
      int hbase = hk & 56;
      for (int r = 0; r < 4; r++) {
        int jr = jr0 + r;
        float s = acc[r] * qv[nt] * Ks[(b * 256 + jr) * 64 + hk];
        s += __shfl_xor(s, 1);
        s += __shfl_xor(s, 2);
        s += __shfl_xor(s, 4);
        float wg = __expf(s) * krw_r[r] * mj_r[r];
        aden[nt] += wg;
        aout[nt] += wg * V[(b * 256 + jr) * 64 + hbase + d];
      }
    }
  }
  for (int nt = 0; nt < 4; nt++) {
    float o = aout[nt], dn = aden[nt];
    o += __shfl_xor(o, 16); o += __shfl_xor(o, 32);
    dn += __shfl_xor(dn, 16); dn += __shfl_xor(dn, 32);
    aout[nt] = o; aden[nt] = dn;
  }

  __shared__ float red[4][64];
  __shared__ float redden[4][8];
  __shared__ float pav[64];
  __shared__ float hcl[64];
  if (l < 16) {
    for (int nt = 0; nt < 4; nt++) {
      int head = nt * 2 + half8;
      red[w][head * 8 + d] = aout[nt];
      if (d == 0) redden[w][head] = aden[nt];
    }
  }
  __syncthreads();
  if (t < 64) {
    int head = t >> 3;
    float num = red[0][t] + red[1][t] + red[2][t] + red[3][t];
    float den = redden[0][head] + redden[1][head] + redden[2][head] + redden[3][head];
    num *= mi;
    den = fmaxf(den * mi, 1e-6f);
    pav[t] = num / den;
  }
  __syncthreads();
  if (t < 64) {
    float a = 0.f;
    for (int c = 0; c < 64; c++) a += pav[c] * wo[c * 64 + t];
    hcl[t] = hin[bi * 64 + t] + pin[bi * 64 + t] + tanhf(a);
  }
  __syncthreads();
  if (t < 128) {
    float a = 0.f;
    for (int c = 0; c < 64; c++) a += hcl[c] * cq_wkv[c * 128 + t];
    if (t < 64) Kc[bi * 64 + t] = a;
    else        Vc[bi * 64 + t - 64] = a;
  }
}

// ---------------------------------------------------------------------------
// Weight staging: global fp32 [NR x NC] -> LDS bf16 [NR x ST], 1024 threads.
// ---------------------------------------------------------------------------
template <int NR, int NC, int ST>
__device__ __forceinline__ void stage_w(const float* __restrict__ g,
                                        __bf16* wls, int t) {
  constexpr int PER = (NR * NC) >> 10;   // 4 or 8 floats per thread
  int i0 = t * PER;
  int k = i0 / NC, c0 = i0 % NC;
  const float* src = g + k * NC + c0;
  __bf16* dst = wls + k * ST + c0;
#pragma unroll
  for (int m = 0; m < PER; m += 4) {
    float4 v = *reinterpret_cast<const float4*>(src + m);
    dst[m] = f2b(v.x); dst[m + 1] = f2b(v.y);
    dst[m + 2] = f2b(v.z); dst[m + 3] = f2b(v.w);
  }
}

// ---------------------------------------------------------------------------
// K3: fused latent tail, 8 blocks x 1024 threads. All matmuls read LDS-staged
// bf16 weights; cross-attn K/V staged bf16 per 64-row quarter. LDS ~61 KB.
// ---------------------------------------------------------------------------
__global__ __launch_bounds__(1024) void k_tail(
    const float* __restrict__ quer, const float* __restrict__ Kc,
    const float* __restrict__ Vc, const float* __restrict__ mask,
    const float* __restrict__ cq_wq, const float* __restrict__ cq_wo,
    const float* __restrict__ cq_bo,
    const float* __restrict__ sa_wq, const float* __restrict__ sa_wkv,
    const float* __restrict__ sa_wo, const float* __restrict__ sa_bo,
    const float* __restrict__ oq_w, const float* __restrict__ g1,
    const float* __restrict__ b1, const float* __restrict__ w1,
    const float* __restrict__ w2, const float* __restrict__ g2,
    const float* __restrict__ b2v, float* __restrict__ out) {
  int b = blockIdx.x;
  int t = threadIdx.x;

  __shared__ float sq[32 * 68];   // latent state, fp32
  __shared__ float sx[32 * 68];   // q1/qq/x/y
  __shared__ float pool[6400];    // KV-qtr(bf16,4096f) | selfKV(4160f) | ffnh(4096f); soc at +4160
  __shared__ float smask[256];
  __shared__ __bf16 wls[8448];    // staged weights (64x66 / 64x130 / 128x66)

  float* soc = pool + 4160;       // 32*68
  __bf16* kq = reinterpret_cast<__bf16*>(pool);  // [64][64] bf16
  __bf16* vq = kq + 4096;

  const int rr6 = t >> 6, c6 = t & 63;     // matmul-64 mapping
  const int r2 = t >> 5, h = (t >> 2) & 7, s = t & 3;  // attention mapping

  // P0: quer -> sq, mask, stage cq_wq
  {
    float2 qz = *reinterpret_cast<const float2*>(quer + b * 2048 + (t >> 5) * 64 + (t & 31) * 2);
    sq[(t >> 5) * 68 + (t & 31) * 2] = qz.x;
    sq[(t >> 5) * 68 + (t & 31) * 2 + 1] = qz.y;
    if (t < 256) smask[t] = mask[b * 256 + t];
    stage_w<64, 64, 66>(cq_wq, wls, t);
  }
  __syncthreads();

  // P1: q1 = quer @ cq_wq -> sx
  {
    float a0 = 0.f, a1 = 0.f;
#pragma unroll 8
    for (int k = 0; k < 64; k++) {
      float wv = (float)wls[k * 66 + c6];
      a0 += sq[rr6 * 68 + k] * wv;
      a1 += sq[(rr6 + 16) * 68 + k] * wv;
    }
    sx[rr6 * 68 + c6] = a0;
    sx[(rr6 + 16) * 68 + c6] = a1;
  }
  __syncthreads();

  // P2: cross-attn over 4 quarters of 64 nodes (K/V staged bf16 in LDS)
  float num[8] = {0.f, 0.f, 0.f, 0.f, 0.f, 0.f, 0.f, 0.f};
  float den = 0.f;
  {
    float qv8[8];
#pragma unroll
    for (int dd = 0; dd < 8; dd++) qv8[dd] = sx[r2 * 68 + h * 8 + dd];
    for (int qtr = 0; qtr < 4; qtr++) {
      {  // stage K/V quarter: 512 thr each, 8 elems/thread
        int half = t >> 9, idx = t & 511;
        int jl = idx >> 3, c0 = (idx & 7) * 8;
        const float* src = (half ? Vc : Kc) + ((long)(b * 256 + qtr * 64 + jl)) * 64 + c0;
        __bf16* dst = (half ? vq : kq) + jl * 64 + c0;
        float4 u = *reinterpret_cast<const float4*>(src);
        float4 v = *reinterpret_cast<const float4*>(src + 4);
        dst[0] = f2b(u.x); dst[1] = f2b(u.y); dst[2] = f2b(u.z); dst[3] = f2b(u.w);
        dst[4] = f2b(v.x); dst[5] = f2b(v.y); dst[6] = f2b(v.z); dst[7] = f2b(v.w);
      }
      if (qtr == 0) stage_w<64, 64, 66>(cq_wo, wls, t);  // prefetch next weights
      __syncthreads();
#pragma unroll
      for (int jj = 0; jj < 16; jj++) {
        int jl = jj * 4 + s;
        bf16x8 kk = *reinterpret_cast<const bf16x8*>(kq + jl * 64 + h * 8);
        float sc = qv8[0] * (float)kk[0] + qv8[1] * (float)kk[1]
                 + qv8[2] * (float)kk[2] + qv8[3] * (float)kk[3]
                 + qv8[4] * (float)kk[4] + qv8[5] * (float)kk[5]
                 + qv8[6] * (float)kk[6] + qv8[7] * (float)kk[7];
        sc *= ATT_SCALE;
        sc = (smask[qtr * 64 + jl] > 0.5f) ? sc : -1e30f;
        sc = fminf(fmaxf(sc, -5.f), 5.f);
        float ex = __expf(sc);
        den += ex;
        bf16x8 vv = *reinterpret_cast<const bf16x8*>(vq + jl * 64 + h * 8);
#pragma unroll
        for (int dd = 0; dd < 8; dd++) num[dd] += ex * (float)vv[dd];
      }
      __syncthreads();
    }
    den += __shfl_xor(den, 1); den += __shfl_xor(den, 2);
#pragma unroll
    for (int dd = 0; dd < 8; dd++) {
      float v = num[dd];
      v += __shfl_xor(v, 1); v += __shfl_xor(v, 2);
      num[dd] = v;
    }
    if (s == 0) {
      float inv = 1.f / den;
#pragma unroll
      for (int dd = 0; dd < 8; dd++) soc[r2 * 68 + h * 8 + dd] = num[dd] * inv;
    }
  }
  __syncthreads();

  // P4: q = quer + soc @ cq_wo + cq_bo
  {
    float a0 = 0.f, a1 = 0.f;
#pragma unroll 8
    for (int k = 0; k < 64; k++) {
      float wv = (float)wls[k * 66 + c6];
      a0 += soc[rr6 * 68 + k] * wv;
      a1 += soc[(rr6 + 16) * 68 + k] * wv;
    }
    float bb = cq_bo[c6];
    sq[rr6 * 68 + c6] += a0 + bb;
    sq[(rr6 + 16) * 68 + c6] += a1 + bb;
  }
  __syncthreads();

  // Two latent self-attention layers
  for (int layer = 0; layer < 2; layer++) {
    const float* wql = sa_wq + layer * 4096;
    const float* wkvl = sa_wkv + layer * 8192;
    const float* wol = sa_wo + layer * 4096;
    const float* bol = sa_bo + layer * 64;

    stage_w<64, 64, 66>(wql, wls, t);
    __syncthreads();
    {  // qq = sq @ wql -> sx
      float a0 = 0.f, a1 = 0.f;
#pragma unroll 8
      for (int k = 0; k < 64; k++) {
        float wv = (float)wls[k * 66 + c6];
        a0 += sq[rr6 * 68 + k] * wv;
        a1 += sq[(rr6 + 16) * 68 + k] * wv;
      }
      sx[rr6 * 68 + c6] = a0;
      sx[(rr6 + 16) * 68 + c6] = a1;
    }
    __syncthreads();
    stage_w<64, 128, 130>(wkvl, wls, t);
    __syncthreads();
    {  // selfKV: K -> pool[0..2080), V -> pool[2080..4160), stride 65
      int rrk = t >> 7, ck = t & 127;
      float a0 = 0.f, a1 = 0.f, a2 = 0.f, a3 = 0.f;
#pragma unroll 8
      for (int k = 0; k < 64; k++) {
        float wv = (float)wls[k * 130 + ck];
        a0 += sq[rrk * 68 + k] * wv;
        a1 += sq[(rrk + 8) * 68 + k] * wv;
        a2 += sq[(rrk + 16) * 68 + k] * wv;
        a3 += sq[(rrk + 24) * 68 + k] * wv;
      }
      float* dst = (ck < 64) ? (pool + rrk * 65 + ck) : (pool + 2080 + rrk * 65 + (ck - 64));
      dst[0] = a0; dst[8 * 65] = a1; dst[16 * 65] = a2; dst[24 * 65] = a3;
    }
    __syncthreads();
    {  // self-attn scores (8 j per thread) + prefetch wol
      stage_w<64, 64, 66>(wol, wls, t);
      float qv8[8];
#pragma unroll
      for (int dd = 0; dd < 8; dd++) qv8[dd] = sx[r2 * 68 + h * 8 + dd];
      float nm[8] = {0.f, 0.f, 0.f, 0.f, 0.f, 0.f, 0.f, 0.f};
      float dn = 0.f;
#pragma unroll
      for (int jj = 0; jj < 8; jj++) {
        int j = jj * 4 + s;
        const float* kp = pool + j * 65 + h * 8;
        float sc = 0.f;
#pragma unroll
        for (int dd = 0; dd < 8; dd++) sc += qv8[dd] * kp[dd];
        sc *= ATT_SCALE;
        sc = fminf(fmaxf(sc, -5.f), 5.f);
        float ex = __expf(sc);
        dn += ex;
        const float* vp = pool + 2080 + j * 65 + h * 8;
#pragma unroll
        for (int dd = 0; dd < 8; dd++) nm[dd] += ex * vp[dd];
      }
      dn += __shfl_xor(dn, 1); dn += __shfl_xor(dn, 2);
#pragma unroll
      for (int dd = 0; dd < 8; dd++) {
        float v = nm[dd];
        v += __shfl_xor(v, 1); v += __shfl_xor(v, 2);
        nm[dd] = v;
      }
      if (s == 0) {
        float inv = 1.f / dn;
#pragma unroll
        for (int dd = 0; dd < 8; dd++) soc[r2 * 68 + h * 8 + dd] = nm[dd] * inv;
      }
    }
    __syncthreads();
    {  // q += soc @ wol + bol
      float a0 = 0.f, a1 = 0.f;
#pragma unroll 8
      for (int k = 0; k < 64; k++) {
        float wv = (float)wls[k * 66 + c6];
        a0 += soc[rr6 * 68 + k] * wv;
        a1 += soc[(rr6 + 16) * 68 + k] * wv;
      }
      float bb = bol[c6];
      sq[rr6 * 68 + c6] += a0 + bb;
      sq[(rr6 + 16) * 68 + c6] += a1 + bb;
    }
    __syncthreads();
  }

  // Final: x = q @ oq_w ; LN1 ; ffn ; LN2
  stage_w<64, 64, 66>(oq_w, wls, t);
  __syncthreads();
  {
    float a0 = 0.f, a1 = 0.f;
#pragma unroll 8
    for (int k = 0; k < 64; k++) {
      float wv = (float)wls[k * 66 + c6];
      a0 += sq[rr6 * 68 + k] * wv;
      a1 += sq[(rr6 + 16) * 68 + k] * wv;
    }
    sx[rr6 * 68 + c6] = a0;
    sx[(rr6 + 16) * 68 + c6] = a1;
  }
  __syncthreads();
  {  // LN1 in place (wave-local rows) + stage w1
    int wv_ = t >> 6, lc = t & 63;
#pragma unroll
    for (int pass = 0; pass < 2; pass++) {
      int rr = wv_ + pass * 16;
      float x = sx[rr * 68 + lc];
      float m = x;
      for (int off = 1; off < 64; off <<= 1) m += __shfl_xor(m, off);
      m *= (1.f / 64.f);
      float dv = x - m, vv = dv * dv;
      for (int off = 1; off < 64; off <<= 1) vv += __shfl_xor(vv, off);
      vv *= (1.f / 64.f);
      sx[rr * 68 + lc] = dv * rsqrtf(vv + 1e-5f) * g1[lc] + b1[lc];
    }
    stage_w<64, 128, 130>(w1, wls, t);
  }
  __syncthreads();
  {  // ffnh = relu(y @ w1) -> pool stride 128
    int rrk = t >> 7, ck = t & 127;
    float a0 = 0.f, a1 = 0.f, a2 = 0.f, a3 = 0.f;
#pragma unroll 8
    for (int k = 0; k < 64; k++) {
      float wv = (float)wls[k * 130 + ck];
      a0 += sx[rrk * 68 + k] * wv;
      a1 += sx[(rrk + 8) * 68 + k] * wv;
      a2 += sx[(rrk + 16) * 68 + k] * wv;
      a3 += sx[(rrk + 24) * 68 + k] * wv;
    }
    pool[rrk * 128 + ck] = fmaxf(a0, 0.f);
    pool[(rrk + 8) * 128 + ck] = fmaxf(a1, 0.f);
    pool[(rrk + 16) * 128 + ck] = fmaxf(a2, 0.f);
    pool[(rrk + 24) * 128 + ck] = fmaxf(a3, 0.f);
  }
  __syncthreads();
  stage_w<128, 64, 66>(w2, wls, t);
  __syncthreads();
  {  // z = y + ffnh @ w2 ; LN2 ; out
    int wv_ = t >> 6, lc = t & 63;
#pragma unroll
    for (int pass = 0; pass < 2; pass++) {
      int rr = wv_ + pass * 16;
      float ff = 0.f;
#pragma unroll 8
      for (int k = 0; k < 128; k++) ff += pool[rr * 128 + k] * (float)wls[k * 66 + lc];
      float z = sx[rr * 68 + lc] + ff;
      float m2 = z;
      for (int off = 1; off < 64; off <<= 1) m2 += __shfl_xor(m2, off);
      m2 *= (1.f / 64.f);
      float dz = z - m2, v2 = dz * dz;
      for (int off = 1; off < 64; off <<= 1) v2 += __shfl_xor(v2, off);
      v2 *= (1.f / 64.f);
      out[b * 2048 + rr * 64 + lc] = dz * rsqrtf(v2 + 1e-5f) * g2[lc] + b2v[lc];
    }
  }
}

// ---------------------------------------------------------------------------
extern "C" void kernel_launch(void* const* d_in, const int* in_sizes, int n_in,
                              void* d_out, int out_size, void* d_ws, size_t ws_size,
                              hipStream_t stream) {
  const float* h_in   = (const float*)d_in[0];
  const float* p_in   = (const float*)d_in[1];
  const float* e_in   = (const float*)d_in[2];
  const float* krw    = (const float*)d_in[3];
  const float* quer   = (const float*)d_in[4];
  const float* mask   = (const float*)d_in[5];
  const float* wq_p   = (const float*)d_in[6];
  const float* wk_p   = (const float*)d_in[7];
  const float* we_p   = (const float*)d_in[8];
  const float* wv_p   = (const float*)d_in[9];
  const float* wo_p   = (const float*)d_in[10];
  const float* cq_wq  = (const float*)d_in[11];
  const float* cq_wkv = (const float*)d_in[12];
  const float* cq_wo  = (const float*)d_in[13];
  const float* cq_bo  = (const float*)d_in[14];
  const float* sa_wq  = (const float*)d_in[15];
  const float* sa_wkv = (const float*)d_in[16];
  const float* sa_wo  = (const float*)d_in[17];
  const float* sa_bo  = (const float*)d_in[18];
  const float* oq_w   = (const float*)d_in[19];
  const float* ln1_g  = (const float*)d_in[20];
  const float* ln1_b  = (const float*)d_in[21];
  const float* ffn_w1 = (const float*)d_in[22];
  const float* ffn_w2 = (const float*)d_in[23];
  const float* ln2_g  = (const float*)d_in[24];
  const float* ln2_b  = (const float*)d_in[25];

  float* ws = (float*)d_ws;
  float* Q  = ws;              // 131072
  float* Ks = Q + 131072;      // 131072
  float* V  = Ks + 131072;     // 131072
  float* Kc = V + 131072;      // 131072
  float* Vc = Kc + 131072;     // 131072  total 2.6 MB

  k_proj<<<256, 256, 0, stream>>>(p_in, wq_p, wk_p, wv_p, Q, Ks, V);
  k_edge<<<2048, 256, 0, stream>>>(e_in, we_p, krw, mask, h_in, p_in, wo_p, cq_wkv,
                                   Q, Ks, V, Kc, Vc);
  k_tail<<<8, 1024, 0, stream>>>(quer, Kc, Vc, mask, cq_wq, cq_wo, cq_bo,
                                 sa_wq, sa_wkv, sa_wo, sa_bo, oq_w,
                                 ln1_g, ln1_b, ffn_w1, ffn_w2, ln2_g, ln2_b,
                                 (float*)d_out);
}